// Round 1
// baseline (297.983 us; speedup 1.0000x reference)
//
#include <hip/hip_runtime.h>
#include <math.h>

#define TEMP 0.01f

// ---------------------------------------------------------------------------
// ws layout (in floats/ints from base):
//   labels   int[4096]   @ 0
//   cls_v2b  int[64]     @ 4096   (view-2 block index per class, -1 if none)
//   cls_size int[64]     @ 4160   (#members of class)
//   nsum     f32[4096]   @ 4224   (sum of exp over negatives, per row)
//   nmaxb    i32[4096]   @ 8320   (float-bits of max neg exp; e>0 so int max works)
//   pcw      f32[4096]   @ 12416  (sum of cross_w over positives, per row)
//   pcwl     f32[4096]   @ 16512  (sum of cross_w*logit over positives, per row)
//   accum    f32[16]     @ 20608  (0:correct 1:total_pos 2:total_loss)
//   posbuf   f32[4096*128] @ 20624 (per-row positive exp values, dense slots)
// total ~2.08 MB
// ---------------------------------------------------------------------------

__global__ void setup_kernel(const int* __restrict__ ov_raw,
                             int* __restrict__ labels,
                             int* __restrict__ cls_v2b,
                             int* __restrict__ cls_size) {
  __shared__ int ov[32];
  __shared__ int class2[32];
  const int t = threadIdx.x;
  if (t < 64) cls_v2b[t] = -1;
  __syncthreads();
  if (t == 0) {
    // overlap_inds is bool in the reference; harness may pass int32 or raw
    // bytes. Heuristic: if all 32 int32 reads are 0/1, it's int32; else bytes.
    const unsigned char* cp = (const unsigned char*)ov_raw;
    bool as_int = true;
    for (int b = 0; b < 32; ++b) {
      int v = ov_raw[b];
      if (v != 0 && v != 1) { as_int = false; break; }
    }
    int cum = 0;  // exclusive count of non-overlap blocks before b
    for (int b = 0; b < 32; ++b) {
      int o = as_int ? ov_raw[b] : (cp[b] ? 1 : 0);
      ov[b] = o;
      int c2 = o ? b : (32 + cum);
      class2[b] = c2;
      cls_v2b[c2] = b;
      if (!o) cum++;
    }
  }
  __syncthreads();
  if (t < 64) {
    int sz = (t < 32) ? (ov[t] ? 128 : 64) : ((cls_v2b[t] >= 0) ? 64 : 0);
    cls_size[t] = sz;
  }
  for (int i = t; i < 4096; i += 256) {
    labels[i] = (i < 2048) ? (i >> 6) : class2[(i - 2048) >> 6];
  }
}

// 128x128 output tile per block, 8x8 per thread (16x16 thread grid).
// K=128 staged in two 64-deep chunks; LDS layout [k][x] with XOR swizzle.
__global__ __launch_bounds__(256, 2) void main_kernel(
    const float* __restrict__ f1, const float* __restrict__ f2,
    const int* __restrict__ labels, const int* __restrict__ cls_v2b,
    float* __restrict__ nsum, int* __restrict__ nmaxb,
    float* __restrict__ pcw, float* __restrict__ pcwl,
    float* __restrict__ posbuf) {
  __shared__ float As[64][128];
  __shared__ float Bs[64][128];

  const int bi = blockIdx.x, bj = blockIdx.y;
  const int ibase = bi * 128, jbase = bj * 128;
  const float* asrc = (ibase < 2048) ? (f1 + (size_t)ibase * 128)
                                     : (f2 + (size_t)(ibase - 2048) * 128);
  const float* bsrc = (jbase < 2048) ? (f1 + (size_t)jbase * 128)
                                     : (f2 + (size_t)(jbase - 2048) * 128);
  const int t  = threadIdx.x;
  const int tx = t & 15;   // col group (8 cols each)
  const int ty = t >> 4;   // row group (8 rows each)

  float acc[8][8];
#pragma unroll
  for (int r = 0; r < 8; ++r)
#pragma unroll
    for (int c = 0; c < 8; ++c) acc[r][c] = 0.0f;

  const int k4 = t & 15;       // staging: which k-quad (of 16 per chunk)
  const int x0 = t >> 4;       // staging: which row (16 per pass)
  const int fw = (k4 & 7) << 2;  // staging swizzle

  for (int kc = 0; kc < 2; ++kc) {
    if (kc) __syncthreads();  // protect LDS before restaging
    const int kb = kc * 64;
#pragma unroll
    for (int p = 0; p < 8; ++p) {
      const int x = x0 + p * 16;
      const float4 va = *(const float4*)(asrc + (size_t)x * 128 + kb + 4 * k4);
      const float4 vb = *(const float4*)(bsrc + (size_t)x * 128 + kb + 4 * k4);
      const int xs = x ^ fw;
      As[4 * k4 + 0][xs] = va.x; As[4 * k4 + 1][xs] = va.y;
      As[4 * k4 + 2][xs] = va.z; As[4 * k4 + 3][xs] = va.w;
      Bs[4 * k4 + 0][xs] = vb.x; Bs[4 * k4 + 1][xs] = vb.y;
      Bs[4 * k4 + 2][xs] = vb.z; Bs[4 * k4 + 3][xs] = vb.w;
    }
    __syncthreads();

    for (int kq = 0; kq < 16; ++kq) {
      const int f   = (kq & 7) << 2;
      const int xa1 = (8 * ty) ^ f, xa2 = (8 * ty + 4) ^ f;
      const int xb1 = (8 * tx) ^ f, xb2 = (8 * tx + 4) ^ f;
#pragma unroll
      for (int m = 0; m < 4; ++m) {
        const int k = 4 * kq + m;
        const float4 a0 = *(const float4*)&As[k][xa1];
        const float4 a1 = *(const float4*)&As[k][xa2];
        const float4 b0 = *(const float4*)&Bs[k][xb1];
        const float4 b1 = *(const float4*)&Bs[k][xb2];
        const float av[8] = {a0.x, a0.y, a0.z, a0.w, a1.x, a1.y, a1.z, a1.w};
        const float bv[8] = {b0.x, b0.y, b0.z, b0.w, b1.x, b1.y, b1.z, b1.w};
#pragma unroll
        for (int r = 0; r < 8; ++r)
#pragma unroll
          for (int c = 0; c < 8; ++c)
            acc[r][c] = fmaf(av[r], bv[c], acc[r][c]);
      }
    }
  }

  // ---------------- fused epilogue ----------------
  const int gi0 = ibase + 8 * ty;
  const int gj0 = jbase + 8 * tx;
  int li[8], lj[8];
#pragma unroll
  for (int r = 0; r < 8; ++r) li[r] = labels[gi0 + r];
#pragma unroll
  for (int c = 0; c < 8; ++c) lj[c] = labels[gj0 + c];
  const float cw = ((ibase < 2048) != (jbase < 2048)) ? 0.5f : 1.0f;

  float rnsum[8], rnmax[8], rpcw[8], rpcwl[8];
#pragma unroll
  for (int r = 0; r < 8; ++r) {
    rnsum[r] = 0.0f; rnmax[r] = 0.0f; rpcw[r] = 0.0f; rpcwl[r] = 0.0f;
  }

#pragma unroll
  for (int r = 0; r < 8; ++r) {
    const int gi = gi0 + r;
#pragma unroll
    for (int c = 0; c < 8; ++c) {
      const int gj = gj0 + c;
      if (gi == gj) continue;  // eye
      const float logit = acc[r][c] * TEMP;
      const float e = __expf(logit);
      if (li[r] == lj[c]) {
        rpcw[r]  += cw;
        rpcwl[r] += cw * logit;
        const int cc = li[r];
        int slot;
        if (gj < 2048) slot = gj - (cc << 6);
        else slot = ((cc < 32) ? 64 : 0) + (gj - 2048 - (cls_v2b[cc] << 6));
        posbuf[(size_t)gi * 128 + slot] = e;
      } else {
        rnsum[r] += e;
        rnmax[r] = fmaxf(rnmax[r], e);
      }
    }
  }

  // reduce across the 16 col-group lanes (contiguous within a wave)
#pragma unroll
  for (int r = 0; r < 8; ++r) {
    for (int m = 1; m < 16; m <<= 1) {
      rnsum[r] += __shfl_xor(rnsum[r], m, 64);
      rpcw[r]  += __shfl_xor(rpcw[r], m, 64);
      rpcwl[r] += __shfl_xor(rpcwl[r], m, 64);
      rnmax[r] = fmaxf(rnmax[r], __shfl_xor(rnmax[r], m, 64));
    }
  }
  if (tx == 0) {
#pragma unroll
    for (int r = 0; r < 8; ++r) {
      const int gi = gi0 + r;
      atomicAdd(&nsum[gi], rnsum[r]);
      atomicAdd(&pcw[gi],  rpcw[r]);
      atomicAdd(&pcwl[gi], rpcwl[r]);
      atomicMax(&nmaxb[gi], __float_as_int(rnmax[r]));
    }
  }
}

// one wave per row
__global__ void finalize_rows(
    const int* __restrict__ labels, const int* __restrict__ cls_v2b,
    const int* __restrict__ cls_size, const float* __restrict__ nsum,
    const int* __restrict__ nmaxb, const float* __restrict__ pcw,
    const float* __restrict__ pcwl, const float* __restrict__ posbuf,
    float* __restrict__ accum) {
  const int gid = blockIdx.x * blockDim.x + threadIdx.x;
  const int row = gid >> 6;
  const int lane = threadIdx.x & 63;
  if (row >= 4096) return;
  const int c = labels[row];
  const int size = cls_size[c];
  int selfslot;
  if (row < 2048) selfslot = row - (c << 6);
  else selfslot = ((c < 32) ? 64 : 0) + (row - 2048 - (cls_v2b[c] << 6));
  const float nmax = __int_as_float(nmaxb[row]);
  int cnt = 0;
  for (int s0 = 0; s0 < 128; s0 += 64) {
    const int s = s0 + lane;
    bool hit = false;
    if (s < size && s != selfslot) {
      hit = posbuf[(size_t)row * 128 + s] > nmax;
    }
    unsigned long long b = __ballot(hit);
    if (lane == 0) cnt += __popcll(b);
  }
  if (lane == 0) {
    const float rowloss = logf(nsum[row]) * pcw[row] - pcwl[row];
    atomicAdd(&accum[0], (float)cnt);
    atomicAdd(&accum[1], (float)(size - 1));
    atomicAdd(&accum[2], rowloss);
  }
}

__global__ void write_out(const float* __restrict__ accum,
                          float* __restrict__ out) {
  if (threadIdx.x == 0) {
    const float tp = accum[1];
    out[0] = accum[0] / tp;  // acc
    out[1] = accum[2] / tp;  // loss
  }
}

extern "C" void kernel_launch(void* const* d_in, const int* in_sizes, int n_in,
                              void* d_out, int out_size, void* d_ws,
                              size_t ws_size, hipStream_t stream) {
  const float* f1 = (const float*)d_in[0];
  const float* f2 = (const float*)d_in[1];
  const int* ov = (const int*)d_in[2];
  float* out = (float*)d_out;

  float* wsf = (float*)d_ws;
  int* wsi = (int*)d_ws;
  int* labels   = wsi;            // 4096
  int* cls_v2b  = wsi + 4096;     // 64
  int* cls_size = wsi + 4160;     // 64
  float* nsum   = wsf + 4224;     // 4096
  int* nmaxb    = wsi + 8320;     // 4096
  float* pcw    = wsf + 12416;    // 4096
  float* pcwl   = wsf + 16512;    // 4096
  float* accum  = wsf + 20608;    // 16
  float* posbuf = wsf + 20624;    // 4096*128

  // zero nsum/nmaxb/pcw/pcwl/accum in one shot (contiguous)
  hipMemsetAsync(nsum, 0, (size_t)(4 * 4096 + 16) * sizeof(float), stream);

  setup_kernel<<<1, 256, 0, stream>>>(ov, labels, cls_v2b, cls_size);

  dim3 grid(32, 32);
  main_kernel<<<grid, 256, 0, stream>>>(f1, f2, labels, cls_v2b, nsum, nmaxb,
                                        pcw, pcwl, posbuf);

  finalize_rows<<<1024, 256, 0, stream>>>(labels, cls_v2b, cls_size, nsum,
                                          nmaxb, pcw, pcwl, posbuf, accum);

  write_out<<<1, 64, 0, stream>>>(accum, out);
}

// Round 2
// 146.467 us; speedup vs baseline: 2.0345x; 2.0345x over previous
//
#include <hip/hip_runtime.h>
#include <math.h>

#define TEMP 0.01f

// ---------------------------------------------------------------------------
// ws layout (in floats/ints from base):
//   labels   int[4096]   @ 0
//   cls_v2b  int[64]     @ 4096   (view-2 block index per class, -1 if none)
//   cls_size int[64]     @ 4160   (#members of class)
//   nsum     f32[4096]   @ 4224   (neg-exp sum; finalize overwrites w/ size-1)
//   nmaxb    i32[4096]   @ 8320   (float-bits of max neg exp)
//   pcw      f32[4096]   @ 12416  (sum cross_w; finalize overwrites w/ rowloss)
//   pcwl     f32[4096]   @ 16512  (sum cw*logit; finalize overwrites w/ rowcnt)
//   posbuf   f32[4096*128] @ 20624 (per-row positive exp values, dense slots)
// ---------------------------------------------------------------------------

__global__ void setup_kernel(const int* __restrict__ ov_raw,
                             int* __restrict__ labels,
                             int* __restrict__ cls_v2b,
                             int* __restrict__ cls_size) {
  __shared__ int ov[32];
  __shared__ int class2[32];
  const int t = threadIdx.x;
  if (t < 64) cls_v2b[t] = -1;
  __syncthreads();
  if (t == 0) {
    const unsigned char* cp = (const unsigned char*)ov_raw;
    bool as_int = true;
    for (int b = 0; b < 32; ++b) {
      int v = ov_raw[b];
      if (v != 0 && v != 1) { as_int = false; break; }
    }
    int cum = 0;
    for (int b = 0; b < 32; ++b) {
      int o = as_int ? ov_raw[b] : (cp[b] ? 1 : 0);
      ov[b] = o;
      int c2 = o ? b : (32 + cum);
      class2[b] = c2;
      cls_v2b[c2] = b;
      if (!o) cum++;
    }
  }
  __syncthreads();
  if (t < 64) {
    int sz = (t < 32) ? (ov[t] ? 128 : 64) : ((cls_v2b[t] >= 0) ? 64 : 0);
    cls_size[t] = sz;
  }
  for (int i = t; i < 4096; i += 256) {
    labels[i] = (i < 2048) ? (i >> 6) : class2[(i - 2048) >> 6];
  }
}

// 128x128 output tile per block, 8x8 per thread (16x16 thread grid).
__global__ __launch_bounds__(256, 2) void main_kernel(
    const float* __restrict__ f1, const float* __restrict__ f2,
    const int* __restrict__ labels, const int* __restrict__ cls_v2b,
    float* __restrict__ nsum, int* __restrict__ nmaxb,
    float* __restrict__ pcw, float* __restrict__ pcwl,
    float* __restrict__ posbuf) {
  __shared__ float As[64][128];
  __shared__ float Bs[64][128];

  const int bi = blockIdx.x, bj = blockIdx.y;
  const int ibase = bi * 128, jbase = bj * 128;
  const float* asrc = (ibase < 2048) ? (f1 + (size_t)ibase * 128)
                                     : (f2 + (size_t)(ibase - 2048) * 128);
  const float* bsrc = (jbase < 2048) ? (f1 + (size_t)jbase * 128)
                                     : (f2 + (size_t)(jbase - 2048) * 128);
  const int t  = threadIdx.x;
  const int tx = t & 15;
  const int ty = t >> 4;

  float acc[8][8];
#pragma unroll
  for (int r = 0; r < 8; ++r)
#pragma unroll
    for (int c = 0; c < 8; ++c) acc[r][c] = 0.0f;

  const int k4 = t & 15;
  const int x0 = t >> 4;
  const int fw = (k4 & 7) << 2;

  for (int kc = 0; kc < 2; ++kc) {
    if (kc) __syncthreads();
    const int kb = kc * 64;
#pragma unroll
    for (int p = 0; p < 8; ++p) {
      const int x = x0 + p * 16;
      const float4 va = *(const float4*)(asrc + (size_t)x * 128 + kb + 4 * k4);
      const float4 vb = *(const float4*)(bsrc + (size_t)x * 128 + kb + 4 * k4);
      const int xs = x ^ fw;
      As[4 * k4 + 0][xs] = va.x; As[4 * k4 + 1][xs] = va.y;
      As[4 * k4 + 2][xs] = va.z; As[4 * k4 + 3][xs] = va.w;
      Bs[4 * k4 + 0][xs] = vb.x; Bs[4 * k4 + 1][xs] = vb.y;
      Bs[4 * k4 + 2][xs] = vb.z; Bs[4 * k4 + 3][xs] = vb.w;
    }
    __syncthreads();

    for (int kq = 0; kq < 16; ++kq) {
      const int f   = (kq & 7) << 2;
      const int xa1 = (8 * ty) ^ f, xa2 = (8 * ty + 4) ^ f;
      const int xb1 = (8 * tx) ^ f, xb2 = (8 * tx + 4) ^ f;
#pragma unroll
      for (int m = 0; m < 4; ++m) {
        const int k = 4 * kq + m;
        const float4 a0 = *(const float4*)&As[k][xa1];
        const float4 a1 = *(const float4*)&As[k][xa2];
        const float4 b0 = *(const float4*)&Bs[k][xb1];
        const float4 b1 = *(const float4*)&Bs[k][xb2];
        const float av[8] = {a0.x, a0.y, a0.z, a0.w, a1.x, a1.y, a1.z, a1.w};
        const float bv[8] = {b0.x, b0.y, b0.z, b0.w, b1.x, b1.y, b1.z, b1.w};
#pragma unroll
        for (int r = 0; r < 8; ++r)
#pragma unroll
          for (int c = 0; c < 8; ++c)
            acc[r][c] = fmaf(av[r], bv[c], acc[r][c]);
      }
    }
  }

  // ---------------- fused epilogue ----------------
  const int gi0 = ibase + 8 * ty;
  const int gj0 = jbase + 8 * tx;
  int li[8], lj[8];
#pragma unroll
  for (int r = 0; r < 8; ++r) li[r] = labels[gi0 + r];
#pragma unroll
  for (int c = 0; c < 8; ++c) lj[c] = labels[gj0 + c];
  const float cw = ((ibase < 2048) != (jbase < 2048)) ? 0.5f : 1.0f;

  float rnsum[8], rnmax[8], rpcw[8], rpcwl[8];
#pragma unroll
  for (int r = 0; r < 8; ++r) {
    rnsum[r] = 0.0f; rnmax[r] = 0.0f; rpcw[r] = 0.0f; rpcwl[r] = 0.0f;
  }

#pragma unroll
  for (int r = 0; r < 8; ++r) {
    const int gi = gi0 + r;
#pragma unroll
    for (int c = 0; c < 8; ++c) {
      const int gj = gj0 + c;
      if (gi == gj) continue;
      const float logit = acc[r][c] * TEMP;
      const float e = __expf(logit);
      if (li[r] == lj[c]) {
        rpcw[r]  += cw;
        rpcwl[r] += cw * logit;
        const int cc = li[r];
        int slot;
        if (gj < 2048) slot = gj - (cc << 6);
        else slot = ((cc < 32) ? 64 : 0) + (gj - 2048 - (cls_v2b[cc] << 6));
        posbuf[(size_t)gi * 128 + slot] = e;
      } else {
        rnsum[r] += e;
        rnmax[r] = fmaxf(rnmax[r], e);
      }
    }
  }

#pragma unroll
  for (int r = 0; r < 8; ++r) {
    for (int m = 1; m < 16; m <<= 1) {
      rnsum[r] += __shfl_xor(rnsum[r], m, 64);
      rpcw[r]  += __shfl_xor(rpcw[r], m, 64);
      rpcwl[r] += __shfl_xor(rpcwl[r], m, 64);
      rnmax[r] = fmaxf(rnmax[r], __shfl_xor(rnmax[r], m, 64));
    }
  }
  if (tx == 0) {
#pragma unroll
    for (int r = 0; r < 8; ++r) {
      const int gi = gi0 + r;
      atomicAdd(&nsum[gi], rnsum[r]);
      atomicAdd(&pcw[gi],  rpcw[r]);
      atomicAdd(&pcwl[gi], rpcwl[r]);
      atomicMax(&nmaxb[gi], __float_as_int(rnmax[r]));
    }
  }
}

// one wave per row; NO global atomics — per-row results written in place:
//   pcw[row]  <- rowloss
//   pcwl[row] <- #correct positives in row
//   nsum[row] <- size-1 (row's positive count)
__global__ void finalize_rows(
    const int* __restrict__ labels, const int* __restrict__ cls_v2b,
    const int* __restrict__ cls_size, float* __restrict__ nsum,
    const int* __restrict__ nmaxb, float* __restrict__ pcw,
    float* __restrict__ pcwl, const float* __restrict__ posbuf) {
  const int gid = blockIdx.x * blockDim.x + threadIdx.x;
  const int row = gid >> 6;
  const int lane = threadIdx.x & 63;
  if (row >= 4096) return;
  const int c = labels[row];
  const int size = cls_size[c];
  int selfslot;
  if (row < 2048) selfslot = row - (c << 6);
  else selfslot = ((c < 32) ? 64 : 0) + (row - 2048 - (cls_v2b[c] << 6));
  const float nmax = __int_as_float(nmaxb[row]);
  int cnt = 0;
  for (int s0 = 0; s0 < 128; s0 += 64) {
    const int s = s0 + lane;
    bool hit = false;
    if (s < size && s != selfslot) {
      hit = posbuf[(size_t)row * 128 + s] > nmax;
    }
    unsigned long long b = __ballot(hit);
    if (lane == 0) cnt += __popcll(b);
  }
  if (lane == 0) {
    const float rowloss = logf(nsum[row]) * pcw[row] - pcwl[row];
    pcw[row]  = rowloss;
    pcwl[row] = (float)cnt;
    nsum[row] = (float)(size - 1);
  }
}

// single block: tree-reduce the 4096 per-row triples, write both outputs
__global__ void reduce_out(const float* __restrict__ pcw,
                           const float* __restrict__ pcwl,
                           const float* __restrict__ nsum,
                           float* __restrict__ out) {
  __shared__ float sl[4], sc[4], st[4];
  const int t = threadIdx.x;
  float l = 0.f, c = 0.f, tp = 0.f;
  for (int i = t; i < 4096; i += 256) {
    l += pcw[i]; c += pcwl[i]; tp += nsum[i];
  }
  for (int m = 1; m < 64; m <<= 1) {
    l  += __shfl_xor(l, m, 64);
    c  += __shfl_xor(c, m, 64);
    tp += __shfl_xor(tp, m, 64);
  }
  const int w = t >> 6;
  if ((t & 63) == 0) { sl[w] = l; sc[w] = c; st[w] = tp; }
  __syncthreads();
  if (t == 0) {
    l = sl[0] + sl[1] + sl[2] + sl[3];
    c = sc[0] + sc[1] + sc[2] + sc[3];
    tp = st[0] + st[1] + st[2] + st[3];
    out[0] = c / tp;   // acc
    out[1] = l / tp;   // loss
  }
}

extern "C" void kernel_launch(void* const* d_in, const int* in_sizes, int n_in,
                              void* d_out, int out_size, void* d_ws,
                              size_t ws_size, hipStream_t stream) {
  const float* f1 = (const float*)d_in[0];
  const float* f2 = (const float*)d_in[1];
  const int* ov = (const int*)d_in[2];
  float* out = (float*)d_out;

  float* wsf = (float*)d_ws;
  int* wsi = (int*)d_ws;
  int* labels   = wsi;            // 4096
  int* cls_v2b  = wsi + 4096;     // 64
  int* cls_size = wsi + 4160;     // 64
  float* nsum   = wsf + 4224;     // 4096
  int* nmaxb    = wsi + 8320;     // 4096
  float* pcw    = wsf + 12416;    // 4096
  float* pcwl   = wsf + 16512;    // 4096
  float* posbuf = wsf + 20624;    // 4096*128

  // zero nsum/nmaxb/pcw/pcwl (contiguous)
  hipMemsetAsync(nsum, 0, (size_t)(4 * 4096) * sizeof(float), stream);

  setup_kernel<<<1, 256, 0, stream>>>(ov, labels, cls_v2b, cls_size);

  dim3 grid(32, 32);
  main_kernel<<<grid, 256, 0, stream>>>(f1, f2, labels, cls_v2b, nsum, nmaxb,
                                        pcw, pcwl, posbuf);

  finalize_rows<<<1024, 256, 0, stream>>>(labels, cls_v2b, cls_size, nsum,
                                          nmaxb, pcw, pcwl, posbuf);

  reduce_out<<<1, 256, 0, stream>>>(pcw, pcwl, nsum, out);
}

// Round 4
// 110.639 us; speedup vs baseline: 2.6933x; 1.3238x over previous
//
#include <hip/hip_runtime.h>
#include <math.h>

#define TEMP 0.01f

typedef __attribute__((ext_vector_type(8))) short short8;
typedef __attribute__((ext_vector_type(4))) float f32x4;
typedef __attribute__((ext_vector_type(4))) unsigned short ushort4_t;

// ---------------------------------------------------------------------------
// ws layout (floats from base):
//   nsum   f32[4096] @ 0       (sum exp over negatives, per row)
//   nmaxb  i32[4096] @ 4096    (float-bits of max neg exp; exp>0 so int-max ok)
//   pcw    f32[4096] @ 8192    (sum cross_w over positives)
//   pcwl   f32[4096] @ 12288   (sum cross_w*logit over positives)
//   accum  f32[3]    @ 16384   (0:correct 1:total_pos 2:total_loss)
//   counter int      @ 16387
//   posbuf f32[4096*128] @ 16400 (per-row positive exp values, dense slots)
// memset zeroes floats [0, 16392).
// ---------------------------------------------------------------------------

__device__ __forceinline__ unsigned bf16_hi_bits(float x) {
  unsigned u = __float_as_uint(x);
  return (u + 0x7FFFu + ((u >> 16) & 1u)) >> 16;  // RNE to bf16
}

struct HL { unsigned short h, l; };

__device__ __forceinline__ HL split1(float x) {
  unsigned hb = bf16_hi_bits(x);
  float hf = __uint_as_float(hb << 16);
  unsigned lb = bf16_hi_bits(x - hf);
  HL r;
  r.h = (unsigned short)hb;
  r.l = (unsigned short)lb;
  return r;
}

// Decode overlap_inds (robust to int32 vs byte bool) into shared arrays.
// Must be called with full block; uses wave 0; caller must __syncthreads after.
__device__ __forceinline__ void decode_ov(const int* __restrict__ ov_raw,
                                          int* s_class2, int* s_v2b,
                                          int* s_ov) {
  const int t = threadIdx.x;
  if (t < 64) {
    int v = (t < 32) ? ov_raw[t] : 0;
    bool valid = (t >= 32) || (v == 0) || (v == 1);
    unsigned long long okmask = __ballot(valid);
    bool as_int = (okmask == ~0ull);
    s_v2b[t] = 0;
    if (t < 32) {
      int o = as_int ? v : (((const unsigned char*)ov_raw)[t] ? 1 : 0);
      s_ov[t] = o;
      unsigned long long nz = __ballot((t < 32) && !o);
      int cum = __popcll(nz & ((1ull << t) - 1ull));
      int c2 = o ? t : 32 + cum;
      s_class2[t] = c2;
      s_v2b[c2] = t;  // wave-ordered after the init store above
    }
  }
}

__device__ __forceinline__ int labf(int g, const int* s_class2) {
  return (g < 2048) ? (g >> 6) : s_class2[(g - 2048) >> 6];
}

// 128x128 output tile per block; 4 waves in 2x2; each wave 64x64 via
// 4x4 grid of 16x16x32 bf16 MFMA tiles, 3 MFMAs per tile (split fp32).
__global__ __launch_bounds__(256, 2) void main_kernel(
    const float* __restrict__ f1, const float* __restrict__ f2,
    const int* __restrict__ ov_raw, float* __restrict__ nsum,
    int* __restrict__ nmaxb, float* __restrict__ pcw,
    float* __restrict__ pcwl, float* __restrict__ posbuf) {
  __shared__ unsigned short Ah[128][64], Al[128][64];
  __shared__ unsigned short Bh[128][64], Bl[128][64];
  __shared__ int s_class2[32], s_v2b[64], s_ov[32];

  decode_ov(ov_raw, s_class2, s_v2b, s_ov);

  const int ibase = blockIdx.x * 128, jbase = blockIdx.y * 128;
  const float* asrc = (ibase < 2048) ? (f1 + (size_t)ibase * 128)
                                     : (f2 + (size_t)(ibase - 2048) * 128);
  const float* bsrc = (jbase < 2048) ? (f1 + (size_t)jbase * 128)
                                     : (f2 + (size_t)(jbase - 2048) * 128);
  const int t = threadIdx.x;
  const int l = t & 63;
  const int wid = t >> 6;
  const int wy = wid >> 1, wx = wid & 1;  // wave tile: rows wy*64, cols wx*64
  const int rr = l & 15;                  // frag row/col within 16
  const int q = l >> 4;                   // frag k-quad / D row-quad
  const int sw = l & 7;                   // read-side swizzle (== rr & 7)

  f32x4 acc[4][4];
#pragma unroll
  for (int mi = 0; mi < 4; ++mi)
#pragma unroll
    for (int ni = 0; ni < 4; ++ni) acc[mi][ni] = (f32x4)0.0f;

  // staging indices: thread t handles k-quad kq of rows r0+16p
  const int kq = t & 15;
  const int r0 = t >> 4;
  const int stc = ((kq >> 1) ^ (r0 & 7)) * 8 + (kq & 1) * 4;  // ushort idx

  for (int kc = 0; kc < 2; ++kc) {  // K chunks of 64
    if (kc) __syncthreads();
#pragma unroll
    for (int p = 0; p < 8; ++p) {
      const int r = r0 + 16 * p;
      const float4 va = *(const float4*)(asrc + (size_t)r * 128 + kc * 64 + kq * 4);
      const float4 vb = *(const float4*)(bsrc + (size_t)r * 128 + kc * 64 + kq * 4);
      ushort4_t ha, la, hb, lb;
      HL s;
      s = split1(va.x); ha.x = s.h; la.x = s.l;
      s = split1(va.y); ha.y = s.h; la.y = s.l;
      s = split1(va.z); ha.z = s.h; la.z = s.l;
      s = split1(va.w); ha.w = s.h; la.w = s.l;
      s = split1(vb.x); hb.x = s.h; lb.x = s.l;
      s = split1(vb.y); hb.y = s.h; lb.y = s.l;
      s = split1(vb.z); hb.z = s.h; lb.z = s.l;
      s = split1(vb.w); hb.w = s.h; lb.w = s.l;
      *(ushort4_t*)&Ah[r][stc] = ha;
      *(ushort4_t*)&Al[r][stc] = la;
      *(ushort4_t*)&Bh[r][stc] = hb;
      *(ushort4_t*)&Bl[r][stc] = lb;
    }
    __syncthreads();

#pragma unroll
    for (int s = 0; s < 2; ++s) {  // two K=32 steps per chunk
      const int pb = ((((s << 2) | q)) ^ sw) << 3;  // phys ushort offset
      short8 afh[4], afl[4], bfh[4], bfl[4];
#pragma unroll
      for (int mi = 0; mi < 4; ++mi) {
        const int ar = wy * 64 + mi * 16 + rr;
        afh[mi] = *(const short8*)&Ah[ar][pb];
        afl[mi] = *(const short8*)&Al[ar][pb];
        const int br = wx * 64 + mi * 16 + rr;
        bfh[mi] = *(const short8*)&Bh[br][pb];
        bfl[mi] = *(const short8*)&Bl[br][pb];
      }
#pragma unroll
      for (int mi = 0; mi < 4; ++mi)
#pragma unroll
        for (int ni = 0; ni < 4; ++ni) {
          acc[mi][ni] = __builtin_amdgcn_mfma_f32_16x16x32_bf16(
              afh[mi], bfh[ni], acc[mi][ni], 0, 0, 0);
          acc[mi][ni] = __builtin_amdgcn_mfma_f32_16x16x32_bf16(
              afh[mi], bfl[ni], acc[mi][ni], 0, 0, 0);
          acc[mi][ni] = __builtin_amdgcn_mfma_f32_16x16x32_bf16(
              afl[mi], bfh[ni], acc[mi][ni], 0, 0, 0);
        }
    }
  }

  // ---------------- fused epilogue ----------------
  // D layout: col = lane&15 (=rr), row = (lane>>4)*4 + reg (=q*4+reg)
  const float cw = ((ibase < 2048) != (jbase < 2048)) ? 0.5f : 1.0f;
  int gj[4], lj[4];
#pragma unroll
  for (int ni = 0; ni < 4; ++ni) {
    gj[ni] = jbase + wx * 64 + ni * 16 + rr;
    lj[ni] = labf(gj[ni], s_class2);
  }

#pragma unroll
  for (int mi = 0; mi < 4; ++mi) {
#pragma unroll
    for (int reg = 0; reg < 4; ++reg) {
      const int gi = ibase + wy * 64 + mi * 16 + q * 4 + reg;
      const int li = labf(gi, s_class2);
      float rnsum = 0.f, rnmax = 0.f, rpcw = 0.f, rpcwl = 0.f;
#pragma unroll
      for (int ni = 0; ni < 4; ++ni) {
        const int gjj = gj[ni];
        if (gi == gjj) continue;
        const float logit = acc[mi][ni][reg] * TEMP;
        const float e = __expf(logit);
        if (li == lj[ni]) {
          rpcw += cw;
          rpcwl += cw * logit;
          int slot;
          if (gjj < 2048) slot = gjj - (li << 6);
          else slot = ((li < 32) ? 64 : 0) + (gjj - 2048 - (s_v2b[li] << 6));
          posbuf[(size_t)gi * 128 + slot] = e;
        } else {
          rnsum += e;
          rnmax = fmaxf(rnmax, e);
        }
      }
      // reduce across the 16 col lanes (xor of low 4 lane bits keeps q)
#pragma unroll
      for (int m = 1; m < 16; m <<= 1) {
        rnsum += __shfl_xor(rnsum, m, 64);
        rpcw  += __shfl_xor(rpcw, m, 64);
        rpcwl += __shfl_xor(rpcwl, m, 64);
        rnmax = fmaxf(rnmax, __shfl_xor(rnmax, m, 64));
      }
      if (rr == 0) {
        atomicAdd(&nsum[gi], rnsum);
        atomicAdd(&pcw[gi], rpcw);
        atomicAdd(&pcwl[gi], rpcwl);
        atomicMax(&nmaxb[gi], __float_as_int(rnmax));
      }
    }
  }
}

// 64 blocks x 256; block b handles rows 64b..64b+63 (one wave per 16 rows).
// Accumulates correct/total_pos/total_loss; last block writes the 2 outputs.
__global__ __launch_bounds__(256) void finalize_kernel(
    const int* __restrict__ ov_raw, const float* __restrict__ nsum,
    const int* __restrict__ nmaxb, const float* __restrict__ pcw,
    const float* __restrict__ pcwl, const float* __restrict__ posbuf,
    float* __restrict__ accum, int* __restrict__ counter,
    float* __restrict__ out) {
  __shared__ int s_class2[32], s_v2b[64], s_ov[32];
  __shared__ float sc[4], sp[4], sl[4];
  decode_ov(ov_raw, s_class2, s_v2b, s_ov);
  __syncthreads();

  const int t = threadIdx.x;
  const int w = t >> 6, lane = t & 63;
  float cnt_acc = 0.f, pos_acc = 0.f, loss_acc = 0.f;
  const int rbase = blockIdx.x * 64 + w * 16;
  for (int i = 0; i < 16; ++i) {
    const int row = rbase + i;
    const float2 pv = *(const float2*)&posbuf[(size_t)row * 128 + lane * 2];
    const int c = labf(row, s_class2);
    const int size = (c < 32) ? (s_ov[c] ? 128 : 64) : 64;
    int selfslot;
    if (row < 2048) selfslot = row - (c << 6);
    else selfslot = ((c < 32) ? 64 : 0) + (row - 2048 - (s_v2b[c] << 6));
    const float nmax = __int_as_float(nmaxb[row]);
    const int s0 = lane * 2;
    int h = 0;
    if (s0 < size && s0 != selfslot && pv.x > nmax) h++;
    if (s0 + 1 < size && s0 + 1 != selfslot && pv.y > nmax) h++;
    cnt_acc += (float)h;
    if (lane == 0) {
      loss_acc += logf(nsum[row]) * pcw[row] - pcwl[row];
      pos_acc += (float)(size - 1);
    }
  }
#pragma unroll
  for (int m = 1; m < 64; m <<= 1) {
    cnt_acc += __shfl_xor(cnt_acc, m, 64);
    pos_acc += __shfl_xor(pos_acc, m, 64);
    loss_acc += __shfl_xor(loss_acc, m, 64);
  }
  if (lane == 0) { sc[w] = cnt_acc; sp[w] = pos_acc; sl[w] = loss_acc; }
  __syncthreads();
  if (t == 0) {
    atomicAdd(&accum[0], sc[0] + sc[1] + sc[2] + sc[3]);
    atomicAdd(&accum[1], sp[0] + sp[1] + sp[2] + sp[3]);
    atomicAdd(&accum[2], sl[0] + sl[1] + sl[2] + sl[3]);
    __threadfence();
    const int prev = atomicAdd(counter, 1);
    if (prev == 63) {
      const float c = atomicAdd(&accum[0], 0.0f);
      const float tp = atomicAdd(&accum[1], 0.0f);
      const float lo = atomicAdd(&accum[2], 0.0f);
      out[0] = c / tp;
      out[1] = lo / tp;
    }
  }
}

extern "C" void kernel_launch(void* const* d_in, const int* in_sizes, int n_in,
                              void* d_out, int out_size, void* d_ws,
                              size_t ws_size, hipStream_t stream) {
  const float* f1 = (const float*)d_in[0];
  const float* f2 = (const float*)d_in[1];
  const int* ov = (const int*)d_in[2];
  float* out = (float*)d_out;

  float* wsf = (float*)d_ws;
  int* wsi = (int*)d_ws;
  float* nsum   = wsf;            // 4096
  int* nmaxb    = wsi + 4096;     // 4096
  float* pcw    = wsf + 8192;     // 4096
  float* pcwl   = wsf + 12288;    // 4096
  float* accum  = wsf + 16384;    // 3
  int* counter  = wsi + 16387;    // 1
  float* posbuf = wsf + 16400;    // 4096*128

  (void)hipMemsetAsync(nsum, 0, (size_t)16392 * sizeof(float), stream);

  dim3 grid(32, 32);
  main_kernel<<<grid, 256, 0, stream>>>(f1, f2, ov, nsum, nmaxb, pcw, pcwl,
                                        posbuf);
  finalize_kernel<<<64, 256, 0, stream>>>(ov, nsum, nmaxb, pcw, pcwl, posbuf,
                                          accum, counter, out);
}

// Round 5
// 109.668 us; speedup vs baseline: 2.7171x; 1.0089x over previous
//
#include <hip/hip_runtime.h>
#include <math.h>

#define TEMP 0.01f

typedef __attribute__((ext_vector_type(8))) short short8;
typedef __attribute__((ext_vector_type(4))) float f32x4;
typedef __attribute__((ext_vector_type(4))) unsigned short ushort4_t;
typedef __attribute__((ext_vector_type(8))) unsigned short ushort8_t;

// ---------------------------------------------------------------------------
// ws layout (floats from base):
//   nsum   f32[4096] @ 0       (sum exp over negatives, per row)
//   nmaxb  i32[4096] @ 4096    (float-bits of max neg exp; exp>0 so int-max ok)
//   pcw    f32[4096] @ 8192    (sum cross_w over positives)
//   pcwl   f32[4096] @ 12288   (sum cross_w*logit over positives)
//   accum  f32[3]    @ 16384   (0:correct 1:total_pos 2:total_loss)
//   counter int      @ 16387
//   posbuf f32[4096*128] @ 16400
//   Ph     ushort[4096*128] @ float 540688   (bf16-hi plane, swizzled granules)
//   Pl     ushort[4096*128] after Ph         (bf16-lo plane)
// fat path needs 4,259,904 bytes; falls back to legacy kernel otherwise.
// memset zeroes floats [0, 16392).
// ---------------------------------------------------------------------------

__device__ __forceinline__ unsigned bf16_hi_bits(float x) {
  unsigned u = __float_as_uint(x);
  return (u + 0x7FFFu + ((u >> 16) & 1u)) >> 16;  // RNE to bf16
}

struct HL { unsigned short h, l; };

__device__ __forceinline__ HL split1(float x) {
  unsigned hb = bf16_hi_bits(x);
  float hf = __uint_as_float(hb << 16);
  unsigned lb = bf16_hi_bits(x - hf);
  HL r;
  r.h = (unsigned short)hb;
  r.l = (unsigned short)lb;
  return r;
}

// Decode overlap_inds (robust to int32 vs byte bool) into shared arrays.
__device__ __forceinline__ void decode_ov(const int* __restrict__ ov_raw,
                                          int* s_class2, int* s_v2b,
                                          int* s_ov) {
  const int t = threadIdx.x;
  if (t < 64) {
    int v = (t < 32) ? ov_raw[t] : 0;
    bool valid = (t >= 32) || (v == 0) || (v == 1);
    unsigned long long okmask = __ballot(valid);
    bool as_int = (okmask == ~0ull);
    s_v2b[t] = 0;
    if (t < 32) {
      int o = as_int ? v : (((const unsigned char*)ov_raw)[t] ? 1 : 0);
      s_ov[t] = o;
      unsigned long long nz = __ballot((t < 32) && !o);
      int cum = __popcll(nz & ((1ull << t) - 1ull));
      int c2 = o ? t : 32 + cum;
      s_class2[t] = c2;
      s_v2b[c2] = t;
    }
  }
}

__device__ __forceinline__ int labf(int g, const int* s_class2) {
  return (g < 2048) ? (g >> 6) : s_class2[(g - 2048) >> 6];
}

// ---------------------------------------------------------------------------
// Precompute: split all 4096 rows into bf16 hi/lo planes once.
// Record layout per row: 16 granules of 8 ushorts; granule gid = c*4 + gp
// (c = K-chunk of 32, gp = physical granule) holds logical k-range
// c*32 + (gp ^ ((row>>1)&3))*8 .. +8  (XOR swizzle baked in for LDS banks).
// ---------------------------------------------------------------------------
__global__ __launch_bounds__(256) void precompute_kernel(
    const float* __restrict__ f1, const float* __restrict__ f2,
    unsigned short* __restrict__ Ph, unsigned short* __restrict__ Pl) {
  const int t = blockIdx.x * 256 + threadIdx.x;  // 65536 threads
  const int row = t >> 4;
  const int gid = t & 15;
  const int gp = gid & 3, c = gid >> 2;
  const int glog = gp ^ ((row >> 1) & 3);
  const int k = c * 32 + glog * 8;
  const float* src = (row < 2048) ? (f1 + (size_t)row * 128)
                                  : (f2 + (size_t)(row - 2048) * 128);
  const float4 a = *(const float4*)(src + k);
  const float4 b = *(const float4*)(src + k + 4);
  ushort8_t hi, lo;
  HL s;
  s = split1(a.x); hi.s0 = s.h; lo.s0 = s.l;
  s = split1(a.y); hi.s1 = s.h; lo.s1 = s.l;
  s = split1(a.z); hi.s2 = s.h; lo.s2 = s.l;
  s = split1(a.w); hi.s3 = s.h; lo.s3 = s.l;
  s = split1(b.x); hi.s4 = s.h; lo.s4 = s.l;
  s = split1(b.y); hi.s5 = s.h; lo.s5 = s.l;
  s = split1(b.z); hi.s6 = s.h; lo.s6 = s.l;
  s = split1(b.w); hi.s7 = s.h; lo.s7 = s.l;
  *(ushort8_t*)&Ph[(size_t)row * 128 + gid * 8] = hi;
  *(ushort8_t*)&Pl[(size_t)row * 128 + gid * 8] = lo;
}

// ---------------------------------------------------------------------------
// Fat main: 128x128 tile/block, 4 waves 2x2, 64x64/wave, 4 K-chunks of 32.
// Staging = pure 16B load + ds_write_b128 from precomputed planes.
// MFMA order identical to the round-4 kernel (bit-identical results).
// ---------------------------------------------------------------------------
__global__ __launch_bounds__(256, 3) void main_kernel_fat(
    const unsigned short* __restrict__ Ph, const unsigned short* __restrict__ Pl,
    const int* __restrict__ ov_raw, float* __restrict__ nsum,
    int* __restrict__ nmaxb, float* __restrict__ pcw,
    float* __restrict__ pcwl, float* __restrict__ posbuf) {
  __shared__ unsigned short Ah[128][32], Al[128][32];
  __shared__ unsigned short Bh[128][32], Bl[128][32];
  __shared__ int s_class2[32], s_v2b[64], s_ov[32];

  decode_ov(ov_raw, s_class2, s_v2b, s_ov);

  const int ibase = blockIdx.x * 128, jbase = blockIdx.y * 128;
  const int t = threadIdx.x;
  const int l = t & 63;
  const int w = t >> 6;
  const int wy = w >> 1, wx = w & 1;
  const int rr = l & 15;
  const int q = l >> 4;
  const int gp = q ^ ((rr >> 1) & 3);  // phys granule for fragment reads

  f32x4 acc[4][4];
#pragma unroll
  for (int mi = 0; mi < 4; ++mi)
#pragma unroll
    for (int ni = 0; ni < 4; ++ni) acc[mi][ni] = (f32x4)0.0f;

  // staging: lane l copies granule sg of row (32w + 16j + srow)
  const int srow = l >> 2;
  const int sg = l & 3;

  for (int c = 0; c < 4; ++c) {
    if (c) __syncthreads();
    const int goff = c * 32 + sg * 8;  // record ushort offset of this granule
#pragma unroll
    for (int j = 0; j < 2; ++j) {
      const int rb = w * 32 + j * 16;
      const int r = rb + srow;
      const size_t arec = (size_t)(ibase + r) * 128 + goff;
      const size_t brec = (size_t)(jbase + r) * 128 + goff;
      const ushort8_t vah = *(const ushort8_t*)&Ph[arec];
      const ushort8_t val = *(const ushort8_t*)&Pl[arec];
      const ushort8_t vbh = *(const ushort8_t*)&Ph[brec];
      const ushort8_t vbl = *(const ushort8_t*)&Pl[brec];
      *(ushort8_t*)&Ah[r][sg * 8] = vah;
      *(ushort8_t*)&Al[r][sg * 8] = val;
      *(ushort8_t*)&Bh[r][sg * 8] = vbh;
      *(ushort8_t*)&Bl[r][sg * 8] = vbl;
    }
    __syncthreads();

    short8 bfh[4], bfl[4];
#pragma unroll
    for (int ni = 0; ni < 4; ++ni) {
      const int br = wx * 64 + ni * 16 + rr;
      bfh[ni] = *(const short8*)&Bh[br][gp * 8];
      bfl[ni] = *(const short8*)&Bl[br][gp * 8];
    }
#pragma unroll
    for (int mi = 0; mi < 4; ++mi) {
      const int ar = wy * 64 + mi * 16 + rr;
      const short8 afh = *(const short8*)&Ah[ar][gp * 8];
      const short8 afl = *(const short8*)&Al[ar][gp * 8];
#pragma unroll
      for (int ni = 0; ni < 4; ++ni) {
        acc[mi][ni] = __builtin_amdgcn_mfma_f32_16x16x32_bf16(
            afh, bfh[ni], acc[mi][ni], 0, 0, 0);
        acc[mi][ni] = __builtin_amdgcn_mfma_f32_16x16x32_bf16(
            afh, bfl[ni], acc[mi][ni], 0, 0, 0);
        acc[mi][ni] = __builtin_amdgcn_mfma_f32_16x16x32_bf16(
            afl, bfh[ni], acc[mi][ni], 0, 0, 0);
      }
    }
  }

  // ---------------- fused epilogue ----------------
  const float cw = ((ibase < 2048) != (jbase < 2048)) ? 0.5f : 1.0f;
  int gj[4], lj[4];
#pragma unroll
  for (int ni = 0; ni < 4; ++ni) {
    gj[ni] = jbase + wx * 64 + ni * 16 + rr;
    lj[ni] = labf(gj[ni], s_class2);
  }

#pragma unroll
  for (int mi = 0; mi < 4; ++mi) {
#pragma unroll
    for (int reg = 0; reg < 4; ++reg) {
      const int gi = ibase + wy * 64 + mi * 16 + q * 4 + reg;
      const int li = labf(gi, s_class2);
      float rnsum = 0.f, rnmax = 0.f, rpcw = 0.f, rpcwl = 0.f;
#pragma unroll
      for (int ni = 0; ni < 4; ++ni) {
        const int gjj = gj[ni];
        if (gi == gjj) continue;
        const float logit = acc[mi][ni][reg] * TEMP;
        const float e = __expf(logit);
        if (li == lj[ni]) {
          rpcw += cw;
          rpcwl += cw * logit;
          int slot;
          if (gjj < 2048) slot = gjj - (li << 6);
          else slot = ((li < 32) ? 64 : 0) + (gjj - 2048 - (s_v2b[li] << 6));
          posbuf[(size_t)gi * 128 + slot] = e;
        } else {
          rnsum += e;
          rnmax = fmaxf(rnmax, e);
        }
      }
#pragma unroll
      for (int m = 1; m < 16; m <<= 1) {
        rnsum += __shfl_xor(rnsum, m, 64);
        rpcw  += __shfl_xor(rpcw, m, 64);
        rpcwl += __shfl_xor(rpcwl, m, 64);
        rnmax = fmaxf(rnmax, __shfl_xor(rnmax, m, 64));
      }
      if (rr == 0) {
        atomicAdd(&nsum[gi], rnsum);
        atomicAdd(&pcw[gi], rpcw);
        atomicAdd(&pcwl[gi], rpcwl);
        atomicMax(&nmaxb[gi], __float_as_int(rnmax));
      }
    }
  }
}

// ---------------------------------------------------------------------------
// Legacy main (round-4, proven): in-kernel split, used if ws too small.
// ---------------------------------------------------------------------------
__global__ __launch_bounds__(256, 2) void main_kernel_legacy(
    const float* __restrict__ f1, const float* __restrict__ f2,
    const int* __restrict__ ov_raw, float* __restrict__ nsum,
    int* __restrict__ nmaxb, float* __restrict__ pcw,
    float* __restrict__ pcwl, float* __restrict__ posbuf) {
  __shared__ unsigned short Ah[128][64], Al[128][64];
  __shared__ unsigned short Bh[128][64], Bl[128][64];
  __shared__ int s_class2[32], s_v2b[64], s_ov[32];

  decode_ov(ov_raw, s_class2, s_v2b, s_ov);

  const int ibase = blockIdx.x * 128, jbase = blockIdx.y * 128;
  const float* asrc = (ibase < 2048) ? (f1 + (size_t)ibase * 128)
                                     : (f2 + (size_t)(ibase - 2048) * 128);
  const float* bsrc = (jbase < 2048) ? (f1 + (size_t)jbase * 128)
                                     : (f2 + (size_t)(jbase - 2048) * 128);
  const int t = threadIdx.x;
  const int l = t & 63;
  const int wid = t >> 6;
  const int wy = wid >> 1, wx = wid & 1;
  const int rr = l & 15;
  const int q = l >> 4;
  const int sw = l & 7;

  f32x4 acc[4][4];
#pragma unroll
  for (int mi = 0; mi < 4; ++mi)
#pragma unroll
    for (int ni = 0; ni < 4; ++ni) acc[mi][ni] = (f32x4)0.0f;

  const int kq = t & 15;
  const int r0 = t >> 4;
  const int stc = ((kq >> 1) ^ (r0 & 7)) * 8 + (kq & 1) * 4;

  for (int kc = 0; kc < 2; ++kc) {
    if (kc) __syncthreads();
#pragma unroll
    for (int p = 0; p < 8; ++p) {
      const int r = r0 + 16 * p;
      const float4 va = *(const float4*)(asrc + (size_t)r * 128 + kc * 64 + kq * 4);
      const float4 vb = *(const float4*)(bsrc + (size_t)r * 128 + kc * 64 + kq * 4);
      ushort4_t ha, la, hb, lb;
      HL s;
      s = split1(va.x); ha.x = s.h; la.x = s.l;
      s = split1(va.y); ha.y = s.h; la.y = s.l;
      s = split1(va.z); ha.z = s.h; la.z = s.l;
      s = split1(va.w); ha.w = s.h; la.w = s.l;
      s = split1(vb.x); hb.x = s.h; lb.x = s.l;
      s = split1(vb.y); hb.y = s.h; lb.y = s.l;
      s = split1(vb.z); hb.z = s.h; lb.z = s.l;
      s = split1(vb.w); hb.w = s.h; lb.w = s.l;
      *(ushort4_t*)&Ah[r][stc] = ha;
      *(ushort4_t*)&Al[r][stc] = la;
      *(ushort4_t*)&Bh[r][stc] = hb;
      *(ushort4_t*)&Bl[r][stc] = lb;
    }
    __syncthreads();

#pragma unroll
    for (int s = 0; s < 2; ++s) {
      const int pb = ((((s << 2) | q)) ^ sw) << 3;
      short8 afh[4], afl[4], bfh[4], bfl[4];
#pragma unroll
      for (int mi = 0; mi < 4; ++mi) {
        const int ar = wy * 64 + mi * 16 + rr;
        afh[mi] = *(const short8*)&Ah[ar][pb];
        afl[mi] = *(const short8*)&Al[ar][pb];
        const int br = wx * 64 + mi * 16 + rr;
        bfh[mi] = *(const short8*)&Bh[br][pb];
        bfl[mi] = *(const short8*)&Bl[br][pb];
      }
#pragma unroll
      for (int mi = 0; mi < 4; ++mi)
#pragma unroll
        for (int ni = 0; ni < 4; ++ni) {
          acc[mi][ni] = __builtin_amdgcn_mfma_f32_16x16x32_bf16(
              afh[mi], bfh[ni], acc[mi][ni], 0, 0, 0);
          acc[mi][ni] = __builtin_amdgcn_mfma_f32_16x16x32_bf16(
              afh[mi], bfl[ni], acc[mi][ni], 0, 0, 0);
          acc[mi][ni] = __builtin_amdgcn_mfma_f32_16x16x32_bf16(
              afl[mi], bfh[ni], acc[mi][ni], 0, 0, 0);
        }
    }
  }

  const float cw = ((ibase < 2048) != (jbase < 2048)) ? 0.5f : 1.0f;
  int gj[4], lj[4];
#pragma unroll
  for (int ni = 0; ni < 4; ++ni) {
    gj[ni] = jbase + wx * 64 + ni * 16 + rr;
    lj[ni] = labf(gj[ni], s_class2);
  }

#pragma unroll
  for (int mi = 0; mi < 4; ++mi) {
#pragma unroll
    for (int reg = 0; reg < 4; ++reg) {
      const int gi = ibase + wy * 64 + mi * 16 + q * 4 + reg;
      const int li = labf(gi, s_class2);
      float rnsum = 0.f, rnmax = 0.f, rpcw = 0.f, rpcwl = 0.f;
#pragma unroll
      for (int ni = 0; ni < 4; ++ni) {
        const int gjj = gj[ni];
        if (gi == gjj) continue;
        const float logit = acc[mi][ni][reg] * TEMP;
        const float e = __expf(logit);
        if (li == lj[ni]) {
          rpcw += cw;
          rpcwl += cw * logit;
          int slot;
          if (gjj < 2048) slot = gjj - (li << 6);
          else slot = ((li < 32) ? 64 : 0) + (gjj - 2048 - (s_v2b[li] << 6));
          posbuf[(size_t)gi * 128 + slot] = e;
        } else {
          rnsum += e;
          rnmax = fmaxf(rnmax, e);
        }
      }
#pragma unroll
      for (int m = 1; m < 16; m <<= 1) {
        rnsum += __shfl_xor(rnsum, m, 64);
        rpcw  += __shfl_xor(rpcw, m, 64);
        rpcwl += __shfl_xor(rpcwl, m, 64);
        rnmax = fmaxf(rnmax, __shfl_xor(rnmax, m, 64));
      }
      if (rr == 0) {
        atomicAdd(&nsum[gi], rnsum);
        atomicAdd(&pcw[gi], rpcw);
        atomicAdd(&pcwl[gi], rpcwl);
        atomicMax(&nmaxb[gi], __float_as_int(rnmax));
      }
    }
  }
}

// 64 blocks x 256; last block writes the 2 outputs.
__global__ __launch_bounds__(256) void finalize_kernel(
    const int* __restrict__ ov_raw, const float* __restrict__ nsum,
    const int* __restrict__ nmaxb, const float* __restrict__ pcw,
    const float* __restrict__ pcwl, const float* __restrict__ posbuf,
    float* __restrict__ accum, int* __restrict__ counter,
    float* __restrict__ out) {
  __shared__ int s_class2[32], s_v2b[64], s_ov[32];
  __shared__ float sc[4], sp[4], sl[4];
  decode_ov(ov_raw, s_class2, s_v2b, s_ov);
  __syncthreads();

  const int t = threadIdx.x;
  const int w = t >> 6, lane = t & 63;
  float cnt_acc = 0.f, pos_acc = 0.f, loss_acc = 0.f;
  const int rbase = blockIdx.x * 64 + w * 16;
  for (int i = 0; i < 16; ++i) {
    const int row = rbase + i;
    const float2 pv = *(const float2*)&posbuf[(size_t)row * 128 + lane * 2];
    const int c = labf(row, s_class2);
    const int size = (c < 32) ? (s_ov[c] ? 128 : 64) : 64;
    int selfslot;
    if (row < 2048) selfslot = row - (c << 6);
    else selfslot = ((c < 32) ? 64 : 0) + (row - 2048 - (s_v2b[c] << 6));
    const float nmax = __int_as_float(nmaxb[row]);
    const int s0 = lane * 2;
    int h = 0;
    if (s0 < size && s0 != selfslot && pv.x > nmax) h++;
    if (s0 + 1 < size && s0 + 1 != selfslot && pv.y > nmax) h++;
    cnt_acc += (float)h;
    if (lane == 0) {
      loss_acc += logf(nsum[row]) * pcw[row] - pcwl[row];
      pos_acc += (float)(size - 1);
    }
  }
#pragma unroll
  for (int m = 1; m < 64; m <<= 1) {
    cnt_acc += __shfl_xor(cnt_acc, m, 64);
    pos_acc += __shfl_xor(pos_acc, m, 64);
    loss_acc += __shfl_xor(loss_acc, m, 64);
  }
  if (lane == 0) { sc[w] = cnt_acc; sp[w] = pos_acc; sl[w] = loss_acc; }
  __syncthreads();
  if (t == 0) {
    atomicAdd(&accum[0], sc[0] + sc[1] + sc[2] + sc[3]);
    atomicAdd(&accum[1], sp[0] + sp[1] + sp[2] + sp[3]);
    atomicAdd(&accum[2], sl[0] + sl[1] + sl[2] + sl[3]);
    __threadfence();
    const int prev = atomicAdd(counter, 1);
    if (prev == 63) {
      const float c = atomicAdd(&accum[0], 0.0f);
      const float tp = atomicAdd(&accum[1], 0.0f);
      const float lo = atomicAdd(&accum[2], 0.0f);
      out[0] = c / tp;
      out[1] = lo / tp;
    }
  }
}

extern "C" void kernel_launch(void* const* d_in, const int* in_sizes, int n_in,
                              void* d_out, int out_size, void* d_ws,
                              size_t ws_size, hipStream_t stream) {
  const float* f1 = (const float*)d_in[0];
  const float* f2 = (const float*)d_in[1];
  const int* ov = (const int*)d_in[2];
  float* out = (float*)d_out;

  float* wsf = (float*)d_ws;
  int* wsi = (int*)d_ws;
  float* nsum   = wsf;            // 4096
  int* nmaxb    = wsi + 4096;     // 4096
  float* pcw    = wsf + 8192;     // 4096
  float* pcwl   = wsf + 12288;    // 4096
  float* accum  = wsf + 16384;    // 3
  int* counter  = wsi + 16387;    // 1
  float* posbuf = wsf + 16400;    // 4096*128 -> ends at float 540688
  unsigned short* Ph = (unsigned short*)(wsf + 540688);  // 4096*128 ushort
  unsigned short* Pl = Ph + 524288;

  (void)hipMemsetAsync(nsum, 0, (size_t)16392 * sizeof(float), stream);

  dim3 grid(32, 32);
  if (ws_size >= (size_t)4259904) {
    precompute_kernel<<<256, 256, 0, stream>>>(f1, f2, Ph, Pl);
    main_kernel_fat<<<grid, 256, 0, stream>>>(Ph, Pl, ov, nsum, nmaxb, pcw,
                                              pcwl, posbuf);
  } else {
    main_kernel_legacy<<<grid, 256, 0, stream>>>(f1, f2, ov, nsum, nmaxb, pcw,
                                                 pcwl, posbuf);
  }
  finalize_kernel<<<64, 256, 0, stream>>>(ov, nsum, nmaxb, pcw, pcwl, posbuf,
                                          accum, counter, out);
}

// Round 6
// 108.102 us; speedup vs baseline: 2.7565x; 1.0145x over previous
//
#include <hip/hip_runtime.h>
#include <math.h>

#define TEMP 0.01f

typedef __attribute__((ext_vector_type(8))) short short8;
typedef __attribute__((ext_vector_type(4))) float f32x4;
typedef __attribute__((ext_vector_type(4))) unsigned short ushort4_t;

// ---------------------------------------------------------------------------
// ws layout (floats from base):
//   nsum   f32[4096] @ 0       (sum exp over negatives, per row)
//   nmaxb  i32[4096] @ 4096    (float-bits of max neg exp; exp>0 so int-max ok)
//   pcw    f32[4096] @ 8192    (sum cross_w over positives)
//   pcwl   f32[4096] @ 12288   (sum cross_w*logit over positives)
//   accum  f32[3]    @ 16384   (0:correct 1:total_pos 2:total_loss)
//   counter int      @ 16387
//   posbuf f32[4096*128] @ 16400
// memset zeroes floats [0, 16392).
// ---------------------------------------------------------------------------

__device__ __forceinline__ unsigned bf16_hi_bits(float x) {
  unsigned u = __float_as_uint(x);
  return (u + 0x7FFFu + ((u >> 16) & 1u)) >> 16;  // RNE to bf16
}

struct HL { unsigned short h, l; };

__device__ __forceinline__ HL split1(float x) {
  unsigned hb = bf16_hi_bits(x);
  float hf = __uint_as_float(hb << 16);
  unsigned lb = bf16_hi_bits(x - hf);
  HL r;
  r.h = (unsigned short)hb;
  r.l = (unsigned short)lb;
  return r;
}

// Decode overlap_inds (robust to int32 vs byte bool) into shared arrays.
__device__ __forceinline__ void decode_ov(const int* __restrict__ ov_raw,
                                          int* s_class2, int* s_v2b,
                                          int* s_ov) {
  const int t = threadIdx.x;
  if (t < 64) {
    int v = (t < 32) ? ov_raw[t] : 0;
    bool valid = (t >= 32) || (v == 0) || (v == 1);
    unsigned long long okmask = __ballot(valid);
    bool as_int = (okmask == ~0ull);
    s_v2b[t] = 0;
    if (t < 32) {
      int o = as_int ? v : (((const unsigned char*)ov_raw)[t] ? 1 : 0);
      s_ov[t] = o;
      unsigned long long nz = __ballot((t < 32) && !o);
      int cum = __popcll(nz & ((1ull << t) - 1ull));
      int c2 = o ? t : 32 + cum;
      s_class2[t] = c2;
      s_v2b[c2] = t;
    }
  }
}

__device__ __forceinline__ int labf(int g, const int* s_class2) {
  return (g < 2048) ? (g >> 6) : s_class2[(g - 2048) >> 6];
}

__device__ __forceinline__ int slotf(int g, int cls, const int* s_v2b) {
  if (g < 2048) return g - (cls << 6);
  return ((cls < 32) ? 64 : 0) + (g - 2048 - (s_v2b[cls] << 6));
}

// ---------------------------------------------------------------------------
// Symmetric main: 528 upper-triangular 128x128 tiles (bi <= bj). Round-4
// proven K-loop (in-kernel split, 2 chunks of 64, bit-exact MFMA order).
// Off-diagonal tiles also accumulate transposed (column) stats.
// ---------------------------------------------------------------------------
__global__ __launch_bounds__(256, 2) void main_kernel(
    const float* __restrict__ f1, const float* __restrict__ f2,
    const int* __restrict__ ov_raw, float* __restrict__ nsum,
    int* __restrict__ nmaxb, float* __restrict__ pcw,
    float* __restrict__ pcwl, float* __restrict__ posbuf) {
  __shared__ unsigned short Ah[128][64], Al[128][64];
  __shared__ unsigned short Bh[128][64], Bl[128][64];
  __shared__ int s_class2[32], s_v2b[64], s_ov[32];

  decode_ov(ov_raw, s_class2, s_v2b, s_ov);

  // triangular decode: largest bi with off(bi) <= t, off(b) = b*32 - b(b-1)/2
  const int tt = blockIdx.x;
  int bi = (int)(32.5f - sqrtf(1056.25f - 2.0f * (float)tt));
  while (bi * 32 - bi * (bi - 1) / 2 > tt) --bi;
  while ((bi + 1) * 32 - (bi + 1) * bi / 2 <= tt) ++bi;
  const int bj = bi + (tt - (bi * 32 - bi * (bi - 1) / 2));
  const bool off = (bi != bj);

  const int ibase = bi * 128, jbase = bj * 128;
  const float* asrc = (ibase < 2048) ? (f1 + (size_t)ibase * 128)
                                     : (f2 + (size_t)(ibase - 2048) * 128);
  const float* bsrc = (jbase < 2048) ? (f1 + (size_t)jbase * 128)
                                     : (f2 + (size_t)(jbase - 2048) * 128);
  const int t = threadIdx.x;
  const int l = t & 63;
  const int wid = t >> 6;
  const int wy = wid >> 1, wx = wid & 1;
  const int rr = l & 15;
  const int q = l >> 4;
  const int sw = l & 7;

  f32x4 acc[4][4];
#pragma unroll
  for (int mi = 0; mi < 4; ++mi)
#pragma unroll
    for (int ni = 0; ni < 4; ++ni) acc[mi][ni] = (f32x4)0.0f;

  const int kq = t & 15;
  const int r0 = t >> 4;
  const int stc = ((kq >> 1) ^ (r0 & 7)) * 8 + (kq & 1) * 4;

  for (int kc = 0; kc < 2; ++kc) {
    if (kc) __syncthreads();
#pragma unroll
    for (int p = 0; p < 8; ++p) {
      const int r = r0 + 16 * p;
      const float4 va = *(const float4*)(asrc + (size_t)r * 128 + kc * 64 + kq * 4);
      const float4 vb = *(const float4*)(bsrc + (size_t)r * 128 + kc * 64 + kq * 4);
      ushort4_t ha, la, hb, lb;
      HL s;
      s = split1(va.x); ha.x = s.h; la.x = s.l;
      s = split1(va.y); ha.y = s.h; la.y = s.l;
      s = split1(va.z); ha.z = s.h; la.z = s.l;
      s = split1(va.w); ha.w = s.h; la.w = s.l;
      s = split1(vb.x); hb.x = s.h; lb.x = s.l;
      s = split1(vb.y); hb.y = s.h; lb.y = s.l;
      s = split1(vb.z); hb.z = s.h; lb.z = s.l;
      s = split1(vb.w); hb.w = s.h; lb.w = s.l;
      *(ushort4_t*)&Ah[r][stc] = ha;
      *(ushort4_t*)&Al[r][stc] = la;
      *(ushort4_t*)&Bh[r][stc] = hb;
      *(ushort4_t*)&Bl[r][stc] = lb;
    }
    __syncthreads();

#pragma unroll
    for (int s = 0; s < 2; ++s) {
      const int pb = ((((s << 2) | q)) ^ sw) << 3;
      short8 afh[4], afl[4], bfh[4], bfl[4];
#pragma unroll
      for (int mi = 0; mi < 4; ++mi) {
        const int ar = wy * 64 + mi * 16 + rr;
        afh[mi] = *(const short8*)&Ah[ar][pb];
        afl[mi] = *(const short8*)&Al[ar][pb];
        const int br = wx * 64 + mi * 16 + rr;
        bfh[mi] = *(const short8*)&Bh[br][pb];
        bfl[mi] = *(const short8*)&Bl[br][pb];
      }
#pragma unroll
      for (int mi = 0; mi < 4; ++mi)
#pragma unroll
        for (int ni = 0; ni < 4; ++ni) {
          acc[mi][ni] = __builtin_amdgcn_mfma_f32_16x16x32_bf16(
              afh[mi], bfh[ni], acc[mi][ni], 0, 0, 0);
          acc[mi][ni] = __builtin_amdgcn_mfma_f32_16x16x32_bf16(
              afh[mi], bfl[ni], acc[mi][ni], 0, 0, 0);
          acc[mi][ni] = __builtin_amdgcn_mfma_f32_16x16x32_bf16(
              afl[mi], bfh[ni], acc[mi][ni], 0, 0, 0);
        }
    }
  }

  // ---------------- fused epilogue (row + transposed col stats) ----------
  const float cw = ((ibase < 2048) != (jbase < 2048)) ? 0.5f : 1.0f;
  int gj[4], lj[4];
#pragma unroll
  for (int ni = 0; ni < 4; ++ni) {
    gj[ni] = jbase + wx * 64 + ni * 16 + rr;
    lj[ni] = labf(gj[ni], s_class2);
  }

  float cnsum[4], cnmax[4], cpcw[4], cpcwl[4];
#pragma unroll
  for (int ni = 0; ni < 4; ++ni) {
    cnsum[ni] = 0.f; cnmax[ni] = 0.f; cpcw[ni] = 0.f; cpcwl[ni] = 0.f;
  }

#pragma unroll
  for (int mi = 0; mi < 4; ++mi) {
#pragma unroll
    for (int reg = 0; reg < 4; ++reg) {
      const int gi = ibase + wy * 64 + mi * 16 + q * 4 + reg;
      const int li = labf(gi, s_class2);
      float rnsum = 0.f, rnmax = 0.f, rpcw = 0.f, rpcwl = 0.f;
#pragma unroll
      for (int ni = 0; ni < 4; ++ni) {
        const int gjj = gj[ni];
        if (gi == gjj) continue;
        const float logit = acc[mi][ni][reg] * TEMP;
        const float e = __expf(logit);
        if (li == lj[ni]) {
          rpcw += cw;
          rpcwl += cw * logit;
          posbuf[(size_t)gi * 128 + slotf(gjj, li, s_v2b)] = e;
          if (off) {
            cpcw[ni] += cw;
            cpcwl[ni] += cw * logit;
            posbuf[(size_t)gjj * 128 + slotf(gi, li, s_v2b)] = e;
          }
        } else {
          rnsum += e;
          rnmax = fmaxf(rnmax, e);
          if (off) {
            cnsum[ni] += e;
            cnmax[ni] = fmaxf(cnmax[ni], e);
          }
        }
      }
      // row reduce across the 16 col lanes
#pragma unroll
      for (int m = 1; m < 16; m <<= 1) {
        rnsum += __shfl_xor(rnsum, m, 64);
        rpcw  += __shfl_xor(rpcw, m, 64);
        rpcwl += __shfl_xor(rpcwl, m, 64);
        rnmax = fmaxf(rnmax, __shfl_xor(rnmax, m, 64));
      }
      if (rr == 0) {
        atomicAdd(&nsum[gi], rnsum);
        atomicAdd(&pcw[gi], rpcw);
        atomicAdd(&pcwl[gi], rpcwl);
        atomicMax(&nmaxb[gi], __float_as_int(rnmax));
      }
    }
  }

  if (off) {
    // col reduce across the 4 q-groups (lanes xor 16, 32); lanes q==0 commit
#pragma unroll
    for (int ni = 0; ni < 4; ++ni) {
      float cs = cnsum[ni], cm = cnmax[ni], cp = cpcw[ni], cl = cpcwl[ni];
#pragma unroll
      for (int m = 16; m < 64; m <<= 1) {
        cs += __shfl_xor(cs, m, 64);
        cp += __shfl_xor(cp, m, 64);
        cl += __shfl_xor(cl, m, 64);
        cm = fmaxf(cm, __shfl_xor(cm, m, 64));
      }
      if (q == 0) {
        const int g = gj[ni];
        atomicAdd(&nsum[g], cs);
        atomicAdd(&pcw[g], cp);
        atomicAdd(&pcwl[g], cl);
        atomicMax(&nmaxb[g], __float_as_int(cm));
      }
    }
  }
}

// 64 blocks x 256; last block writes the 2 outputs.
__global__ __launch_bounds__(256) void finalize_kernel(
    const int* __restrict__ ov_raw, const float* __restrict__ nsum,
    const int* __restrict__ nmaxb, const float* __restrict__ pcw,
    const float* __restrict__ pcwl, const float* __restrict__ posbuf,
    float* __restrict__ accum, int* __restrict__ counter,
    float* __restrict__ out) {
  __shared__ int s_class2[32], s_v2b[64], s_ov[32];
  __shared__ float sc[4], sp[4], sl[4];
  decode_ov(ov_raw, s_class2, s_v2b, s_ov);
  __syncthreads();

  const int t = threadIdx.x;
  const int w = t >> 6, lane = t & 63;
  float cnt_acc = 0.f, pos_acc = 0.f, loss_acc = 0.f;
  const int rbase = blockIdx.x * 64 + w * 16;
  for (int i = 0; i < 16; ++i) {
    const int row = rbase + i;
    const float2 pv = *(const float2*)&posbuf[(size_t)row * 128 + lane * 2];
    const int c = labf(row, s_class2);
    const int size = (c < 32) ? (s_ov[c] ? 128 : 64) : 64;
    int selfslot;
    if (row < 2048) selfslot = row - (c << 6);
    else selfslot = ((c < 32) ? 64 : 0) + (row - 2048 - (s_v2b[c] << 6));
    const float nmax = __int_as_float(nmaxb[row]);
    const int s0 = lane * 2;
    int h = 0;
    if (s0 < size && s0 != selfslot && pv.x > nmax) h++;
    if (s0 + 1 < size && s0 + 1 != selfslot && pv.y > nmax) h++;
    cnt_acc += (float)h;
    if (lane == 0) {
      loss_acc += logf(nsum[row]) * pcw[row] - pcwl[row];
      pos_acc += (float)(size - 1);
    }
  }
#pragma unroll
  for (int m = 1; m < 64; m <<= 1) {
    cnt_acc += __shfl_xor(cnt_acc, m, 64);
    pos_acc += __shfl_xor(pos_acc, m, 64);
    loss_acc += __shfl_xor(loss_acc, m, 64);
  }
  if (lane == 0) { sc[w] = cnt_acc; sp[w] = pos_acc; sl[w] = loss_acc; }
  __syncthreads();
  if (t == 0) {
    atomicAdd(&accum[0], sc[0] + sc[1] + sc[2] + sc[3]);
    atomicAdd(&accum[1], sp[0] + sp[1] + sp[2] + sp[3]);
    atomicAdd(&accum[2], sl[0] + sl[1] + sl[2] + sl[3]);
    __threadfence();
    const int prev = atomicAdd(counter, 1);
    if (prev == 63) {
      const float c = atomicAdd(&accum[0], 0.0f);
      const float tp = atomicAdd(&accum[1], 0.0f);
      const float lo = atomicAdd(&accum[2], 0.0f);
      out[0] = c / tp;
      out[1] = lo / tp;
    }
  }
}

extern "C" void kernel_launch(void* const* d_in, const int* in_sizes, int n_in,
                              void* d_out, int out_size, void* d_ws,
                              size_t ws_size, hipStream_t stream) {
  const float* f1 = (const float*)d_in[0];
  const float* f2 = (const float*)d_in[1];
  const int* ov = (const int*)d_in[2];
  float* out = (float*)d_out;

  float* wsf = (float*)d_ws;
  int* wsi = (int*)d_ws;
  float* nsum   = wsf;            // 4096
  int* nmaxb    = wsi + 4096;     // 4096
  float* pcw    = wsf + 8192;     // 4096
  float* pcwl   = wsf + 12288;    // 4096
  float* accum  = wsf + 16384;    // 3
  int* counter  = wsi + 16387;    // 1
  float* posbuf = wsf + 16400;    // 4096*128

  (void)hipMemsetAsync(nsum, 0, (size_t)16392 * sizeof(float), stream);

  main_kernel<<<528, 256, 0, stream>>>(f1, f2, ov, nsum, nmaxb, pcw, pcwl,
                                       posbuf);
  finalize_kernel<<<64, 256, 0, stream>>>(ov, nsum, nmaxb, pcw, pcwl, posbuf,
                                          accum, counter, out);
}